// Round 9
// baseline (290.477 us; speedup 1.0000x reference)
//
#include <hip/hip_runtime.h>
#include <math.h>

#define TILE_F 1792    // floats per wave tile; worst-case region ~1770 (elongated level-0 ROI)
#define B896   896     // 2-deep pipeline buffer (cnt4 <= 224 float4)
#define MAXIP  4       // pipelined staging iterations: ceil(224/64)
#define MAXI   7       // serial staging iterations: ceil(448/64)

// ---- fused-prefetch slicing (compile-time; sizes fixed by the problem) ----
#define NF4_0 7782400  // 2*256*200*304/4
#define NF4_1 1945600  // 2*256*100*152/4
#define NF4_2 486400   // 2*256*50*76/4
#define NF4_3 121600   // 2*256*25*38/4
#define PFW   16384    // prefetch waves: 8192 blocks * 2
#define SH_0  475      // ceil(NF4_0/PFW)  -> 8 dma16 iters
#define SH_1  119      // ceil(NF4_1/PFW)  -> 2 iters
#define SH_2  30       // ceil(NF4_2/PFW)  -> 1 iter
#define SH_3  8        // ceil(NF4_3/PFW)  -> 1 iter

typedef __attribute__((address_space(3))) void lds_void;
typedef const __attribute__((address_space(1))) void g_void;

__device__ __forceinline__ void dma16(const float* g, float* l) {
  __builtin_amdgcn_global_load_lds((g_void*)g, (lds_void*)l, 16, 0, 0);
}
// Counted vmcnt wait, wave-uniform k. In-order retire => outstanding<=k implies
// everything older than the newest k ops has completed. (Prefetch DMAs are the
// oldest ops in the wave, so every counted wait below remains conservative.)
#define WC(N) case N: asm volatile("s_waitcnt vmcnt(" #N ")" ::: "memory"); break;
__device__ __forceinline__ void wait_vmcnt(int k) {
  switch (k) {
    WC(0) WC(1) WC(2) WC(3) WC(4) WC(5) WC(6) WC(7) WC(8) WC(9) WC(10) WC(11)
    default: asm volatile("s_waitcnt vmcnt(12)" ::: "memory"); break;
  }
}

// 49-lane bilinear 2x2x(2x2) gather + average + store; arrays are unroll-indexed (registers).
#define COMPUTE_STORE(TP, CC)                                                  \
  if (lane < 49) {                                                             \
    float acc = 0.0f;                                                          \
    _Pragma("unroll")                                                          \
    for (int sy = 0; sy < 2; ++sy) {                                           \
      _Pragma("unroll")                                                        \
      for (int sx = 0; sx < 2; ++sx) {                                         \
        const float w00 = (TP)[rT[sy] + Cc0[sx]];                              \
        const float w01 = (TP)[rT[sy] + Cc1[sx]];                              \
        const float w10 = (TP)[rB[sy] + Cc0[sx]];                              \
        const float w11 = (TP)[rB[sy] + Cc1[sx]];                              \
        const float bil = HY[sy] * (HX[sx] * w00 + LX[sx] * w01)               \
                        + LY[sy] * (HX[sx] * w10 + LX[sx] * w11);              \
        acc += (VY[sy] * VX[sx]) * bil;                                        \
      }                                                                        \
    }                                                                          \
    outp[(CC) * 49] = acc * 0.25f;                                             \
  }

__global__ __launch_bounds__(128) void pooler_kernel(
    const float* __restrict__ f0, const float* __restrict__ f1,
    const float* __restrict__ f2, const float* __restrict__ f3,
    const float* __restrict__ boxes, const int* __restrict__ bidx,
    float* __restrict__ out, int N)
{
  __shared__ __align__(16) float tile[2][TILE_F];   // staging tiles
  __shared__ __align__(16) float dummy[2][256];     // prefetch sink (1KB/wave)
  const int tid  = threadIdx.x;
  const int wave = tid >> 6, lane = tid & 63;
  const int n    = blockIdx.y;
  if (n >= N) return;

  // ---- read box meta inputs first (oldest vmem ops after this point are
  //      these, so the compiler can use a counted wait over the prefetch) ----
  const float bx1 = boxes[4*n+0], by1 = boxes[4*n+1];
  const float bx2 = boxes[4*n+2], by2 = boxes[4*n+3];
  const int b = bidx[n];

  // ---- fused sequential prefetch: this wave streams its slice of the
  //      pyramid into a dummy LDS sink. Coverage over all waves = 1x pyramid,
  //      in dispatch order -> sequential HBM front that warms the L3 while
  //      box work proceeds. Values never read; correctness-independent. ----
  {
    float* dmy = dummy[wave];
    const int wid = (blockIdx.y * gridDim.x + blockIdx.x) * 2 + wave;
#define PF(F, NF4, SH, ITERS)                                                  \
    { const int start = wid * (SH);                                            \
      _Pragma("unroll")                                                        \
      for (int i = 0; i < (ITERS); ++i) {                                      \
        const int u = (i << 6) + lane;                                         \
        const int idx = start + u;                                             \
        if (u < (SH) && idx < (NF4))                                           \
          dma16((F) + ((size_t)idx << 2), dmy);                                \
      } }
    PF(f0, NF4_0, SH_0, 8)
    PF(f1, NF4_1, SH_1, 2)
    PF(f2, NF4_2, SH_2, 1)
    PF(f3, NF4_3, SH_3, 1)
#undef PF
  }

  // ---- per-box meta (wave-uniform, recomputed by every lane) ----
  const float area = (bx2 - bx1 + 1.0f) * (by2 - by1 + 1.0f);
  const float s    = sqrtf(area);
  int lvl = (int)floorf(4.0f + log2f(s / 224.0f + 1e-6f));
  lvl = lvl < 2 ? 2 : (lvl > 5 ? 5 : lvl);
  const int li = lvl - 2;

  int H, W; const float* feat; float scale;
  switch (li) {
    case 0:  feat = f0; H = 200; W = 304; scale = 0.25f;    break;
    case 1:  feat = f1; H = 100; W = 152; scale = 0.125f;   break;
    case 2:  feat = f2; H = 50;  W = 76;  scale = 0.0625f;  break;
    default: feat = f3; H = 25;  W = 38;  scale = 0.03125f; break;
  }
  const float x1s = bx1 * scale, y1s = by1 * scale;
  const float roiw = fmaxf(bx2 * scale - x1s, 1.0f);
  const float roih = fmaxf(by2 * scale - y1s, 1.0f);
  const float binw = roiw / 7.0f, binh = roih / 7.0f;
  const float Hm1f = (float)(H - 1), Wm1f = (float)(W - 1);
  const int   Hm1  = H - 1,          Wm1  = W - 1;

  // ---- staged region bounds (samples monotone: first g=0.25, last g=6.75) ----
  const float yA = fminf(fmaxf(y1s + binh * 0.25f, 0.0f), Hm1f);
  const float yB = fminf(fmaxf(y1s + binh * 6.75f, 0.0f), Hm1f);
  const float xA = fminf(fmaxf(x1s + binw * 0.25f, 0.0f), Wm1f);
  const float xB = fminf(fmaxf(x1s + binw * 6.75f, 0.0f), Wm1f);
  const int y_lo  = (int)yA;
  const int y_hi  = min((int)yB + 1, Hm1);
  const int regH  = y_hi - y_lo + 1;
  const int x_lo4 = ((int)xA) & ~3;
  const int x_hi  = min((int)xB + 1, Wm1);
  const int row4  = ((x_hi - x_lo4 + 4) >> 2);
  const int regW4 = row4 << 2;

  // ---- per-lane bin parameters (channel-invariant; lanes 49..63 compute junk) ----
  const int bin = (lane < 49) ? lane : 0;
  const int ph = bin / 7, pw = bin - (bin / 7) * 7;
  int   rT[2], rB[2], Cc0[2], Cc1[2];           // region-relative (LDS paths)
  int   y0a[2], y1a[2], x0a[2], x1a[2];         // absolute (direct path)
  float HY[2], LY[2], VY[2], HX[2], LX[2], VX[2];
#pragma unroll
  for (int t = 0; t < 2; ++t) {
    {
      const float g  = (float)ph + 0.25f + 0.5f * (float)t;
      const float Yf = y1s + binh * g;
      VY[t] = (Yf >= -1.0f && Yf <= (float)H) ? 1.0f : 0.0f;
      const float y = fminf(fmaxf(Yf, 0.0f), Hm1f);
      const int  y0 = (int)y;
      LY[t] = y - (float)y0;  HY[t] = 1.0f - LY[t];
      y0a[t] = y0;  y1a[t] = min(y0 + 1, Hm1);
      rT[t] = (y0 - y_lo) * regW4;
      rB[t] = (y1a[t] - y_lo) * regW4;
    }
    {
      const float g  = (float)pw + 0.25f + 0.5f * (float)t;
      const float Xf = x1s + binw * g;
      VX[t] = (Xf >= -1.0f && Xf <= (float)W) ? 1.0f : 0.0f;
      const float x = fminf(fmaxf(Xf, 0.0f), Wm1f);
      const int  x0 = (int)x;
      LX[t] = x - (float)x0;  HX[t] = 1.0f - LX[t];
      x0a[t] = x0;  x1a[t] = min(x0 + 1, Wm1);
      Cc0[t] = x0 - x_lo4;
      Cc1[t] = x1a[t] - x_lo4;
    }
  }

  // ---- pointers ----
  const size_t planeHW = (size_t)H * W;
  const int    cbase   = (blockIdx.x << 5) + (wave << 4);   // 16 channels per wave
  const float* plane0  = feat + ((size_t)(b * 256 + cbase)) * planeHW
                              + (size_t)y_lo * W;
  float*       outp    = out + ((size_t)n * 256 + cbase) * 49 + lane;
  float*       myt     = tile[wave];

  if (li == 3) {
    // ======== level-3 direct path: plane is 3.8 KB (cache-hot). No LDS, no DMA. ========
    int   off[2][2][4];
    float wt [2][2][4];
#pragma unroll
    for (int sy = 0; sy < 2; ++sy) {
#pragma unroll
      for (int sx = 0; sx < 2; ++sx) {
        const float vv = VY[sy] * VX[sx];
        off[sy][sx][0] = y0a[sy] * 38 + x0a[sx];  wt[sy][sx][0] = vv * HY[sy] * HX[sx];
        off[sy][sx][1] = y0a[sy] * 38 + x1a[sx];  wt[sy][sx][1] = vv * HY[sy] * LX[sx];
        off[sy][sx][2] = y1a[sy] * 38 + x0a[sx];  wt[sy][sx][2] = vv * LY[sy] * HX[sx];
        off[sy][sx][3] = y1a[sy] * 38 + x1a[sx];  wt[sy][sx][3] = vv * LY[sy] * LX[sx];
      }
    }
    const float* pc0 = feat + ((size_t)(b * 256 + cbase)) * planeHW;  // no y_lo offset
#pragma unroll 2
    for (int cc = 0; cc < 16; ++cc) {
      const float* pc = pc0 + (size_t)cc * planeHW;
      float acc = 0.0f;
#pragma unroll
      for (int sy = 0; sy < 2; ++sy)
#pragma unroll
        for (int sx = 0; sx < 2; ++sx)
#pragma unroll
          for (int k = 0; k < 4; ++k)
            acc += wt[sy][sx][k] * pc[off[sy][sx][k]];
      if (lane < 49) outp[cc * 49] = acc * 0.25f;
    }
  } else {
    int cnt4 = regH * row4;
    if (cnt4 > TILE_F / 4) cnt4 = TILE_F / 4;   // safety (analysis: <=~443)
    // exact magic-divide by row4 (u*row4 < 65536 for all paths: 447*76 < 65536)
    const int Mrow = (int)(65536.0f / (float)row4) + 1;
    const int K = (cnt4 + 63) >> 6;

    if (cnt4 <= B896 / 4) {
      // ======== pipelined path: 2 x 896, store-aware counted waits ========
      int soff[MAXIP];
#pragma unroll
      for (int i = 0; i < MAXIP; ++i) {
        const int u = lane + (i << 6);
        if (u < cnt4) {
          const int r = (u * Mrow) >> 16;
          const int c = u - r * row4;
          soff[i] = r * W + x_lo4 + (c << 2);
        } else soff[i] = -1;
      }
      // prologue: channel 0 -> buffer 0
#pragma unroll
      for (int i = 0; i < MAXIP; ++i)
        if (soff[i] >= 0) dma16(plane0 + soff[i], myt + (i << 8));

      for (int cc = 0; cc < 16; ++cc) {
        asm volatile("s_waitcnt lgkmcnt(0)" ::: "memory");
        if (cc + 1 < 16) {
          const float* pl = plane0 + (size_t)(cc + 1) * planeHW;
          float* bf = myt + (((cc + 1) & 1) ? B896 : 0);
#pragma unroll
          for (int i = 0; i < MAXIP; ++i)
            if (soff[i] >= 0) dma16(pl + soff[i], bf + (i << 8));
        }
        wait_vmcnt(cc == 0 ? K : (cc == 15 ? 1 : K + 1));
        const float* bufC = myt + ((cc & 1) ? B896 : 0);
        COMPUTE_STORE(bufC, cc)
      }
    } else {
      // ======== serial fallback (rare elongated boxes): full 1792-float tile ========
      int soff[MAXI];
#pragma unroll
      for (int i = 0; i < MAXI; ++i) {
        const int u = lane + (i << 6);
        if (u < cnt4) {
          const int r = (u * Mrow) >> 16;
          const int c = u - r * row4;
          soff[i] = r * W + x_lo4 + (c << 2);
        } else soff[i] = -1;
      }
      for (int cc = 0; cc < 16; ++cc) {
        const float* plane = plane0 + (size_t)cc * planeHW;
        asm volatile("s_waitcnt lgkmcnt(0)" ::: "memory");
#pragma unroll
        for (int i = 0; i < MAXI; ++i)
          if (soff[i] >= 0) dma16(plane + soff[i], myt + (i << 8));
        asm volatile("s_waitcnt vmcnt(0)" ::: "memory");
        COMPUTE_STORE(myt, cc)
      }
    }
  }
}

extern "C" void kernel_launch(void* const* d_in, const int* in_sizes, int n_in,
                              void* d_out, int out_size, void* d_ws, size_t ws_size,
                              hipStream_t stream) {
  const float* f0    = (const float*)d_in[0];
  const float* f1    = (const float*)d_in[1];
  const float* f2    = (const float*)d_in[2];
  const float* f3    = (const float*)d_in[3];
  const float* boxes = (const float*)d_in[4];
  const int*   bidx  = (const int*)d_in[5];
  const int N = in_sizes[5];                 // 1024 boxes
  dim3 grid(8, N);                           // 8 groups x (2 waves x 16 ch) = 256 channels
  pooler_kernel<<<grid, 128, 0, stream>>>(f0, f1, f2, f3, boxes, bidx,
                                          (float*)d_out, N);
}

// Round 10
// 282.679 us; speedup vs baseline: 1.0276x; 1.0276x over previous
//
#include <hip/hip_runtime.h>
#include <math.h>

#define TILE_F 1792    // floats per wave tile; worst-case region ~1770 (elongated level-0 ROI)
#define B896   896     // 2-deep pipeline buffer (cnt4 <= 224 float4)
#define MAXIP  4       // pipelined staging iterations: ceil(224/64)
#define MAXI   7       // serial staging iterations: ceil(448/64)

typedef __attribute__((address_space(3))) void lds_void;
typedef const __attribute__((address_space(1))) void g_void;

__device__ __forceinline__ void dma16(const float* g, float* l) {
  __builtin_amdgcn_global_load_lds((g_void*)g, (lds_void*)l, 16, 0, 0);
}
// Counted vmcnt wait, wave-uniform k. In-order retire => outstanding<=k implies
// everything older than the newest k ops has completed.
#define WC(N) case N: asm volatile("s_waitcnt vmcnt(" #N ")" ::: "memory"); break;
__device__ __forceinline__ void wait_vmcnt(int k) {
  switch (k) {
    WC(0) WC(1) WC(2) WC(3) WC(4) WC(5) WC(6) WC(7)
    default: asm volatile("s_waitcnt vmcnt(8)" ::: "memory"); break;
  }
}

// 49-lane bilinear 2x2x(2x2) gather + average + store; arrays are unroll-indexed (registers).
#define COMPUTE_STORE(TP, CC)                                                  \
  if (lane < 49) {                                                             \
    float acc = 0.0f;                                                          \
    _Pragma("unroll")                                                          \
    for (int sy = 0; sy < 2; ++sy) {                                           \
      _Pragma("unroll")                                                        \
      for (int sx = 0; sx < 2; ++sx) {                                         \
        const float w00 = (TP)[rT[sy] + Cc0[sx]];                              \
        const float w01 = (TP)[rT[sy] + Cc1[sx]];                              \
        const float w10 = (TP)[rB[sy] + Cc0[sx]];                              \
        const float w11 = (TP)[rB[sy] + Cc1[sx]];                              \
        const float bil = HY[sy] * (HX[sx] * w00 + LX[sx] * w01)               \
                        + LY[sy] * (HX[sx] * w10 + LX[sx] * w11);              \
        acc += (VY[sy] * VX[sx]) * bil;                                        \
      }                                                                        \
    }                                                                          \
    outp[(CC) * 49] = acc * 0.25f;                                             \
  }

// ============ L3 warm-up: stream the whole pyramid sequentially ============
// Each thread reads 4 CONSECUTIVE float4s per iteration (64B/lane, 4KB/wave
// contiguous, 4 independent loads hand-unrolled) -> >=4 loads in flight per
// lane instead of ~1, targeting ~5+ TB/s instead of R7's 3.3.
__global__ __launch_bounds__(256) void warm_kernel(
    const float4* __restrict__ f0, int n0, const float4* __restrict__ f1, int n1,
    const float4* __restrict__ f2, int n2, const float4* __restrict__ f3, int n3)
{
  const int stride = gridDim.x * blockDim.x;     // threads total
  const int idx = blockIdx.x * blockDim.x + threadIdx.x;
  float a0 = 0.f, a1 = 0.f, a2 = 0.f, a3 = 0.f;
#define WARM(F, NN)                                                            \
  { int i = idx * 4;                                                           \
    const int step = stride * 4;                                               \
    for (; i + 3 < (NN); i += step) {                                          \
      float4 v0 = (F)[i];     float4 v1 = (F)[i + 1];                          \
      float4 v2 = (F)[i + 2]; float4 v3 = (F)[i + 3];                          \
      a0 += v0.x + v0.y + v0.z + v0.w;  a1 += v1.x + v1.y + v1.z + v1.w;       \
      a2 += v2.x + v2.y + v2.z + v2.w;  a3 += v3.x + v3.y + v3.z + v3.w;       \
    }                                                                          \
    for (; i < (NN); ++i) { float4 v = (F)[i]; a0 += v.x + v.y + v.z + v.w; } }
  WARM(f0, n0) WARM(f1, n1) WARM(f2, n2) WARM(f3, n3)
#undef WARM
  asm volatile("" :: "v"(a0), "v"(a1), "v"(a2), "v"(a3));  // keep loads live
}

__global__ __launch_bounds__(128) void pooler_kernel(
    const float* __restrict__ f0, const float* __restrict__ f1,
    const float* __restrict__ f2, const float* __restrict__ f3,
    const float* __restrict__ boxes, const int* __restrict__ bidx,
    float* __restrict__ out, int N)
{
  __shared__ __align__(16) float tile[2][TILE_F];  // 14336 B/block -> 11 blocks/CU
  const int tid  = threadIdx.x;
  const int wave = tid >> 6, lane = tid & 63;
  const int n    = blockIdx.y;
  if (n >= N) return;

  // ---- per-box meta (wave-uniform, recomputed by every lane) ----
  const float bx1 = boxes[4*n+0], by1 = boxes[4*n+1];
  const float bx2 = boxes[4*n+2], by2 = boxes[4*n+3];
  const float area = (bx2 - bx1 + 1.0f) * (by2 - by1 + 1.0f);
  const float s    = sqrtf(area);
  int lvl = (int)floorf(4.0f + log2f(s / 224.0f + 1e-6f));
  lvl = lvl < 2 ? 2 : (lvl > 5 ? 5 : lvl);
  const int li = lvl - 2;

  int H, W; const float* feat; float scale;
  switch (li) {
    case 0:  feat = f0; H = 200; W = 304; scale = 0.25f;    break;
    case 1:  feat = f1; H = 100; W = 152; scale = 0.125f;   break;
    case 2:  feat = f2; H = 50;  W = 76;  scale = 0.0625f;  break;
    default: feat = f3; H = 25;  W = 38;  scale = 0.03125f; break;
  }
  const int b = bidx[n];
  const float x1s = bx1 * scale, y1s = by1 * scale;
  const float roiw = fmaxf(bx2 * scale - x1s, 1.0f);
  const float roih = fmaxf(by2 * scale - y1s, 1.0f);
  const float binw = roiw / 7.0f, binh = roih / 7.0f;
  const float Hm1f = (float)(H - 1), Wm1f = (float)(W - 1);
  const int   Hm1  = H - 1,          Wm1  = W - 1;

  // ---- staged region bounds (samples monotone: first g=0.25, last g=6.75) ----
  const float yA = fminf(fmaxf(y1s + binh * 0.25f, 0.0f), Hm1f);
  const float yB = fminf(fmaxf(y1s + binh * 6.75f, 0.0f), Hm1f);
  const float xA = fminf(fmaxf(x1s + binw * 0.25f, 0.0f), Wm1f);
  const float xB = fminf(fmaxf(x1s + binw * 6.75f, 0.0f), Wm1f);
  const int y_lo  = (int)yA;
  const int y_hi  = min((int)yB + 1, Hm1);
  const int regH  = y_hi - y_lo + 1;
  const int x_lo4 = ((int)xA) & ~3;
  const int x_hi  = min((int)xB + 1, Wm1);
  const int row4  = ((x_hi - x_lo4 + 4) >> 2);
  const int regW4 = row4 << 2;

  // ---- per-lane bin parameters (channel-invariant; lanes 49..63 compute junk) ----
  const int bin = (lane < 49) ? lane : 0;
  const int ph = bin / 7, pw = bin - (bin / 7) * 7;
  int   rT[2], rB[2], Cc0[2], Cc1[2];           // region-relative (LDS paths)
  int   y0a[2], y1a[2], x0a[2], x1a[2];         // absolute (direct path)
  float HY[2], LY[2], VY[2], HX[2], LX[2], VX[2];
#pragma unroll
  for (int t = 0; t < 2; ++t) {
    {
      const float g  = (float)ph + 0.25f + 0.5f * (float)t;
      const float Yf = y1s + binh * g;
      VY[t] = (Yf >= -1.0f && Yf <= (float)H) ? 1.0f : 0.0f;
      const float y = fminf(fmaxf(Yf, 0.0f), Hm1f);
      const int  y0 = (int)y;
      LY[t] = y - (float)y0;  HY[t] = 1.0f - LY[t];
      y0a[t] = y0;  y1a[t] = min(y0 + 1, Hm1);
      rT[t] = (y0 - y_lo) * regW4;
      rB[t] = (y1a[t] - y_lo) * regW4;
    }
    {
      const float g  = (float)pw + 0.25f + 0.5f * (float)t;
      const float Xf = x1s + binw * g;
      VX[t] = (Xf >= -1.0f && Xf <= (float)W) ? 1.0f : 0.0f;
      const float x = fminf(fmaxf(Xf, 0.0f), Wm1f);
      const int  x0 = (int)x;
      LX[t] = x - (float)x0;  HX[t] = 1.0f - LX[t];
      x0a[t] = x0;  x1a[t] = min(x0 + 1, Wm1);
      Cc0[t] = x0 - x_lo4;
      Cc1[t] = x1a[t] - x_lo4;
    }
  }

  // ---- pointers ----
  const size_t planeHW = (size_t)H * W;
  const int    cbase   = (blockIdx.x << 5) + (wave << 4);   // 16 channels per wave
  const float* plane0  = feat + ((size_t)(b * 256 + cbase)) * planeHW
                              + (size_t)y_lo * W;
  float*       outp    = out + ((size_t)n * 256 + cbase) * 49 + lane;
  float*       myt     = tile[wave];

  if (li == 3) {
    // ======== level-3 direct path: plane is 3.8 KB (cache-hot). No LDS, no DMA. ========
    int   off[2][2][4];
    float wt [2][2][4];
#pragma unroll
    for (int sy = 0; sy < 2; ++sy) {
#pragma unroll
      for (int sx = 0; sx < 2; ++sx) {
        const float vv = VY[sy] * VX[sx];
        off[sy][sx][0] = y0a[sy] * 38 + x0a[sx];  wt[sy][sx][0] = vv * HY[sy] * HX[sx];
        off[sy][sx][1] = y0a[sy] * 38 + x1a[sx];  wt[sy][sx][1] = vv * HY[sy] * LX[sx];
        off[sy][sx][2] = y1a[sy] * 38 + x0a[sx];  wt[sy][sx][2] = vv * LY[sy] * HX[sx];
        off[sy][sx][3] = y1a[sy] * 38 + x1a[sx];  wt[sy][sx][3] = vv * LY[sy] * LX[sx];
      }
    }
    const float* pc0 = feat + ((size_t)(b * 256 + cbase)) * planeHW;  // no y_lo offset
#pragma unroll 2
    for (int cc = 0; cc < 16; ++cc) {
      const float* pc = pc0 + (size_t)cc * planeHW;
      float acc = 0.0f;
#pragma unroll
      for (int sy = 0; sy < 2; ++sy)
#pragma unroll
        for (int sx = 0; sx < 2; ++sx)
#pragma unroll
          for (int k = 0; k < 4; ++k)
            acc += wt[sy][sx][k] * pc[off[sy][sx][k]];
      if (lane < 49) outp[cc * 49] = acc * 0.25f;
    }
  } else {
    int cnt4 = regH * row4;
    if (cnt4 > TILE_F / 4) cnt4 = TILE_F / 4;   // safety (analysis: <=~443)
    // exact magic-divide by row4 (u*row4 < 65536 for all paths: 447*76 < 65536)
    const int Mrow = (int)(65536.0f / (float)row4) + 1;
    const int K = (cnt4 + 63) >> 6;

    if (cnt4 <= B896 / 4) {
      // ======== pipelined path: 2 x 896, store-aware counted waits ========
      int soff[MAXIP];
#pragma unroll
      for (int i = 0; i < MAXIP; ++i) {
        const int u = lane + (i << 6);
        if (u < cnt4) {
          const int r = (u * Mrow) >> 16;
          const int c = u - r * row4;
          soff[i] = r * W + x_lo4 + (c << 2);
        } else soff[i] = -1;
      }
      // prologue: channel 0 -> buffer 0
#pragma unroll
      for (int i = 0; i < MAXIP; ++i)
        if (soff[i] >= 0) dma16(plane0 + soff[i], myt + (i << 8));

      for (int cc = 0; cc < 16; ++cc) {
        asm volatile("s_waitcnt lgkmcnt(0)" ::: "memory");
        if (cc + 1 < 16) {
          const float* pl = plane0 + (size_t)(cc + 1) * planeHW;
          float* bf = myt + (((cc + 1) & 1) ? B896 : 0);
#pragma unroll
          for (int i = 0; i < MAXIP; ++i)
            if (soff[i] >= 0) dma16(pl + soff[i], bf + (i << 8));
        }
        wait_vmcnt(cc == 0 ? K : (cc == 15 ? 1 : K + 1));
        const float* bufC = myt + ((cc & 1) ? B896 : 0);
        COMPUTE_STORE(bufC, cc)
      }
    } else {
      // ======== serial fallback (rare elongated boxes): full 1792-float tile ========
      int soff[MAXI];
#pragma unroll
      for (int i = 0; i < MAXI; ++i) {
        const int u = lane + (i << 6);
        if (u < cnt4) {
          const int r = (u * Mrow) >> 16;
          const int c = u - r * row4;
          soff[i] = r * W + x_lo4 + (c << 2);
        } else soff[i] = -1;
      }
      for (int cc = 0; cc < 16; ++cc) {
        const float* plane = plane0 + (size_t)cc * planeHW;
        asm volatile("s_waitcnt lgkmcnt(0)" ::: "memory");
#pragma unroll
        for (int i = 0; i < MAXI; ++i)
          if (soff[i] >= 0) dma16(plane + soff[i], myt + (i << 8));
        asm volatile("s_waitcnt vmcnt(0)" ::: "memory");
        COMPUTE_STORE(myt, cc)
      }
    }
  }
}

extern "C" void kernel_launch(void* const* d_in, const int* in_sizes, int n_in,
                              void* d_out, int out_size, void* d_ws, size_t ws_size,
                              hipStream_t stream) {
  const float* f0    = (const float*)d_in[0];
  const float* f1    = (const float*)d_in[1];
  const float* f2    = (const float*)d_in[2];
  const float* f3    = (const float*)d_in[3];
  const float* boxes = (const float*)d_in[4];
  const int*   bidx  = (const int*)d_in[5];
  const int N = in_sizes[5];                 // 1024 boxes

  // Pass 1: sequential L3 warm (consecutive-4 unrolled loads, targets ~5+ TB/s).
  warm_kernel<<<dim3(2048), 256, 0, stream>>>(
      (const float4*)f0, 2*256*200*304/4, (const float4*)f1, 2*256*100*152/4,
      (const float4*)f2, 2*256*50*76/4,   (const float4*)f3, 2*256*25*38/4);

  // Pass 2: pooler — byte-identical to R7's bench (2-deep + level-3 direct).
  dim3 grid(8, N);                           // 8 groups x (2 waves x 16 ch) = 256 channels
  pooler_kernel<<<grid, 128, 0, stream>>>(f0, f1, f2, f3, boxes, bidx,
                                          (float*)d_out, N);
}